// Round 1
// baseline (1078.207 us; speedup 1.0000x reference)
//
#include <hip/hip_runtime.h>

// ---------------------------------------------------------------------------
// 3-layer GraphSAGE (mean aggr, root weight) on MI355X, fp32.
//   per layer: out = mean_{j->i}(x_j) @ Wl + bl + x_i @ Wr   (+relu / +L2norm)
// Strategy:
//   - transform-first (mean is linear): z = h@Wl, w = h@Wr+b, out = agg(z)+w
//   - CSR build per call (deg count -> scan -> scatter), then per-node gather
// ---------------------------------------------------------------------------

// ------------------------- CSR build ---------------------------------------

__global__ void count_deg_kernel(const int* __restrict__ dst, int E,
                                 int* __restrict__ deg) {
  for (int i = blockIdx.x * blockDim.x + threadIdx.x; i < E;
       i += gridDim.x * blockDim.x)
    atomicAdd(&deg[dst[i]], 1);
}

__global__ __launch_bounds__(1024) void scan_kernel(const int* __restrict__ deg,
                                                    int* __restrict__ row_ptr,
                                                    int* __restrict__ cursor,
                                                    int N) {
  __shared__ int sums[1024];
  const int t = threadIdx.x;
  const int chunk = (N + 1023) >> 10;
  const int beg = t * chunk;
  int s = 0;
  for (int j = 0; j < chunk; ++j) {
    int idx = beg + j;
    if (idx < N) s += deg[idx];
  }
  sums[t] = s;
  __syncthreads();
  // inclusive scan (Hillis-Steele)
  for (int d = 1; d < 1024; d <<= 1) {
    int v = (t >= d) ? sums[t - d] : 0;
    __syncthreads();
    sums[t] += v;
    __syncthreads();
  }
  int running = sums[t] - s;  // exclusive prefix for this thread's chunk
  for (int j = 0; j < chunk; ++j) {
    int idx = beg + j;
    if (idx < N) {
      row_ptr[idx] = running;
      cursor[idx] = running;
      running += deg[idx];
    }
  }
  if (t == 1023) row_ptr[N] = sums[1023];
}

__global__ void scatter_kernel(const int* __restrict__ src,
                               const int* __restrict__ dst, int E,
                               int* __restrict__ cursor, int* __restrict__ csr) {
  for (int i = blockIdx.x * blockDim.x + threadIdx.x; i < E;
       i += gridDim.x * blockDim.x) {
    int d = dst[i];
    int p = atomicAdd(&cursor[d], 1);
    csr[p] = src[i];
  }
}

// ------------------------- GEMM: C[N x M] = A[N x 128] @ B[128 x M] (+bias) --
// Tile 128 rows x 64 cols per block of 256 threads, K tiled by 32.
// Per thread: 4 rows x 8 cols micro-tile.

__global__ __launch_bounds__(256) void gemm_k128(const float* __restrict__ A,
                                                 const float* __restrict__ B,
                                                 const float* __restrict__ bias,
                                                 float* __restrict__ C, int N,
                                                 int M) {
  __shared__ float As[128][33];  // +1 pad: conflict-free column reads
  __shared__ float Bs[32][64];
  const int t = threadIdx.x;
  const int rb = blockIdx.y * 128;
  const int cb = blockIdx.x * 64;
  const int ty = t >> 3;  // 0..31 -> 4-row group
  const int tx = t & 7;   // 0..7  -> 8-col group

  float acc[4][8];
#pragma unroll
  for (int r = 0; r < 4; ++r)
#pragma unroll
    for (int c = 0; c < 8; ++c) acc[r][c] = 0.f;

  for (int kt = 0; kt < 128; kt += 32) {
// load A tile (128x32 floats = 1024 float4, 4 per thread)
#pragma unroll
    for (int i = 0; i < 4; ++i) {
      int idx = t + i * 256;
      int lr = idx >> 3, k4 = idx & 7;
      int row = rb + lr;
      float4 v = make_float4(0.f, 0.f, 0.f, 0.f);
      if (row < N)
        v = *(const float4*)(A + (size_t)row * 128 + kt + k4 * 4);
      As[lr][k4 * 4 + 0] = v.x;
      As[lr][k4 * 4 + 1] = v.y;
      As[lr][k4 * 4 + 2] = v.z;
      As[lr][k4 * 4 + 3] = v.w;
    }
// load B tile (32x64 floats = 512 float4, 2 per thread)
#pragma unroll
    for (int i = 0; i < 2; ++i) {
      int idx = t + i * 256;
      int kk = idx >> 4, c4 = idx & 15;
      float4 v = *(const float4*)(B + (size_t)(kt + kk) * M + cb + c4 * 4);
      *(float4*)(&Bs[kk][c4 * 4]) = v;
    }
    __syncthreads();
#pragma unroll
    for (int kk = 0; kk < 32; ++kk) {
      float a0 = As[ty * 4 + 0][kk];
      float a1 = As[ty * 4 + 1][kk];
      float a2 = As[ty * 4 + 2][kk];
      float a3 = As[ty * 4 + 3][kk];
      float4 b0 = *(const float4*)(&Bs[kk][tx * 8]);
      float4 b1 = *(const float4*)(&Bs[kk][tx * 8 + 4]);
      float bb[8] = {b0.x, b0.y, b0.z, b0.w, b1.x, b1.y, b1.z, b1.w};
#pragma unroll
      for (int c = 0; c < 8; ++c) {
        acc[0][c] = fmaf(a0, bb[c], acc[0][c]);
        acc[1][c] = fmaf(a1, bb[c], acc[1][c]);
        acc[2][c] = fmaf(a2, bb[c], acc[2][c]);
        acc[3][c] = fmaf(a3, bb[c], acc[3][c]);
      }
    }
    __syncthreads();
  }

  // epilogue
  float bv[8];
#pragma unroll
  for (int c = 0; c < 8; ++c) bv[c] = bias ? bias[cb + tx * 8 + c] : 0.f;
#pragma unroll
  for (int r = 0; r < 4; ++r) {
    int row = rb + ty * 4 + r;
    if (row >= N) continue;
    float4 o0 = make_float4(acc[r][0] + bv[0], acc[r][1] + bv[1],
                            acc[r][2] + bv[2], acc[r][3] + bv[3]);
    float4 o1 = make_float4(acc[r][4] + bv[4], acc[r][5] + bv[5],
                            acc[r][6] + bv[6], acc[r][7] + bv[7]);
    float* cp = C + (size_t)row * M + cb + tx * 8;
    *(float4*)(cp) = o0;
    *(float4*)(cp + 4) = o1;
  }
}

// ------------------------- aggregation: out = relu(mean(z[nbrs]) + w) -------
// D=128: 32 lanes per node (float4/lane), 8 nodes per 256-thread block.

__global__ __launch_bounds__(256) void agg_combine_relu128(
    const float* __restrict__ z, const float* __restrict__ w,
    const int* __restrict__ row_ptr, const int* __restrict__ csr,
    float* __restrict__ out, int N) {
  const int g = threadIdx.x >> 5;
  const int lane = threadIdx.x & 31;
  const int node = blockIdx.x * 8 + g;
  if (node >= N) return;
  const int s = row_ptr[node];
  const int e = row_ptr[node + 1];
  float4 a0 = make_float4(0.f, 0.f, 0.f, 0.f);
  float4 a1 = make_float4(0.f, 0.f, 0.f, 0.f);
  int i = s;
  for (; i + 1 < e; i += 2) {
    int s0 = csr[i], s1 = csr[i + 1];
    float4 v0 = *(const float4*)(z + (size_t)s0 * 128 + lane * 4);
    float4 v1 = *(const float4*)(z + (size_t)s1 * 128 + lane * 4);
    a0.x += v0.x; a0.y += v0.y; a0.z += v0.z; a0.w += v0.w;
    a1.x += v1.x; a1.y += v1.y; a1.z += v1.z; a1.w += v1.w;
  }
  if (i < e) {
    int s0 = csr[i];
    float4 v0 = *(const float4*)(z + (size_t)s0 * 128 + lane * 4);
    a0.x += v0.x; a0.y += v0.y; a0.z += v0.z; a0.w += v0.w;
  }
  a0.x += a1.x; a0.y += a1.y; a0.z += a1.z; a0.w += a1.w;
  const int d = e - s;
  const float inv = 1.0f / (float)(d > 0 ? d : 1);
  float4 wv = *(const float4*)(w + (size_t)node * 128 + lane * 4);
  float4 o;
  o.x = fmaxf(fmaf(a0.x, inv, wv.x), 0.f);
  o.y = fmaxf(fmaf(a0.y, inv, wv.y), 0.f);
  o.z = fmaxf(fmaf(a0.z, inv, wv.z), 0.f);
  o.w = fmaxf(fmaf(a0.w, inv, wv.w), 0.f);
  *(float4*)(out + (size_t)node * 128 + lane * 4) = o;
}

// D=64 + row L2-normalize: 16 lanes per node, 16 nodes per block.
__global__ __launch_bounds__(256) void agg_combine_norm64(
    const float* __restrict__ z, const float* __restrict__ w,
    const int* __restrict__ row_ptr, const int* __restrict__ csr,
    float* __restrict__ out, int N) {
  const int g = threadIdx.x >> 4;
  const int lane = threadIdx.x & 15;
  const int node = blockIdx.x * 16 + g;
  if (node >= N) return;
  const int s = row_ptr[node];
  const int e = row_ptr[node + 1];
  float4 a0 = make_float4(0.f, 0.f, 0.f, 0.f);
  float4 a1 = make_float4(0.f, 0.f, 0.f, 0.f);
  int i = s;
  for (; i + 1 < e; i += 2) {
    int s0 = csr[i], s1 = csr[i + 1];
    float4 v0 = *(const float4*)(z + (size_t)s0 * 64 + lane * 4);
    float4 v1 = *(const float4*)(z + (size_t)s1 * 64 + lane * 4);
    a0.x += v0.x; a0.y += v0.y; a0.z += v0.z; a0.w += v0.w;
    a1.x += v1.x; a1.y += v1.y; a1.z += v1.z; a1.w += v1.w;
  }
  if (i < e) {
    int s0 = csr[i];
    float4 v0 = *(const float4*)(z + (size_t)s0 * 64 + lane * 4);
    a0.x += v0.x; a0.y += v0.y; a0.z += v0.z; a0.w += v0.w;
  }
  a0.x += a1.x; a0.y += a1.y; a0.z += a1.z; a0.w += a1.w;
  const int d = e - s;
  const float inv = 1.0f / (float)(d > 0 ? d : 1);
  float4 wv = *(const float4*)(w + (size_t)node * 64 + lane * 4);
  float4 v;
  v.x = fmaf(a0.x, inv, wv.x);
  v.y = fmaf(a0.y, inv, wv.y);
  v.z = fmaf(a0.z, inv, wv.z);
  v.w = fmaf(a0.w, inv, wv.w);
  float n2 = v.x * v.x + v.y * v.y + v.z * v.z + v.w * v.w;
  n2 += __shfl_xor(n2, 1);
  n2 += __shfl_xor(n2, 2);
  n2 += __shfl_xor(n2, 4);
  n2 += __shfl_xor(n2, 8);
  const float invn = 1.0f / fmaxf(sqrtf(n2), 1e-12f);
  v.x *= invn; v.y *= invn; v.z *= invn; v.w *= invn;
  *(float4*)(out + (size_t)node * 64 + lane * 4) = v;
}

// ------------------------- launch ------------------------------------------

extern "C" void kernel_launch(void* const* d_in, const int* in_sizes, int n_in,
                              void* d_out, int out_size, void* d_ws,
                              size_t ws_size, hipStream_t stream) {
  const float* x   = (const float*)d_in[0];
  const int*   ei  = (const int*)d_in[1];
  const float* Wl1 = (const float*)d_in[2];
  const float* bl1 = (const float*)d_in[3];
  const float* Wr1 = (const float*)d_in[4];
  const float* Wl2 = (const float*)d_in[5];
  const float* bl2 = (const float*)d_in[6];
  const float* Wr2 = (const float*)d_in[7];
  const float* Wl3 = (const float*)d_in[8];
  const float* bl3 = (const float*)d_in[9];
  const float* Wr3 = (const float*)d_in[10];

  const int N = in_sizes[0] / 128;
  const int E = in_sizes[1] / 2;
  const int* src = ei;       // edge_index[0]
  const int* dst = ei + E;   // edge_index[1]

  char* ws = (char*)d_ws;
  size_t off = 0;
  auto take = [&](size_t bytes) -> char* {
    char* p = ws + off;
    off += (bytes + 255) & ~(size_t)255;
    return p;
  };
  float* h       = (float*)take((size_t)N * 128 * 4);
  float* z       = (float*)take((size_t)N * 128 * 4);
  float* w       = (float*)take((size_t)N * 128 * 4);
  int*   deg     = (int*)take((size_t)N * 4);
  int*   row_ptr = (int*)take((size_t)(N + 1) * 4);
  int*   cursor  = (int*)take((size_t)N * 4);
  int*   csr     = (int*)take((size_t)E * 4);
  (void)ws_size;

  // --- CSR build (per call; edge_index restored before every timed launch)
  hipMemsetAsync(deg, 0, (size_t)N * 4, stream);
  count_deg_kernel<<<2048, 256, 0, stream>>>(dst, E, deg);
  scan_kernel<<<1, 1024, 0, stream>>>(deg, row_ptr, cursor, N);
  scatter_kernel<<<2048, 256, 0, stream>>>(src, dst, E, cursor, csr);

  const dim3 blk(256);
  const dim3 g2(2, (N + 127) / 128);  // M = 128
  const dim3 g1(1, (N + 127) / 128);  // M = 64
  const int aggBlocks128 = (N + 7) / 8;
  const int aggBlocks64  = (N + 15) / 16;

  // --- layer 1: z = x@Wl1, w = x@Wr1+bl1, h = relu(mean-agg(z)+w)
  gemm_k128<<<g2, blk, 0, stream>>>(x, Wl1, nullptr, z, N, 128);
  gemm_k128<<<g2, blk, 0, stream>>>(x, Wr1, bl1, w, N, 128);
  agg_combine_relu128<<<aggBlocks128, blk, 0, stream>>>(z, w, row_ptr, csr, h, N);

  // --- layer 2
  gemm_k128<<<g2, blk, 0, stream>>>(h, Wl2, nullptr, z, N, 128);
  gemm_k128<<<g2, blk, 0, stream>>>(h, Wr2, bl2, w, N, 128);
  agg_combine_relu128<<<aggBlocks128, blk, 0, stream>>>(z, w, row_ptr, csr, h, N);

  // --- layer 3 (width 64) + L2 normalize
  gemm_k128<<<g1, blk, 0, stream>>>(h, Wl3, nullptr, z, N, 64);
  gemm_k128<<<g1, blk, 0, stream>>>(h, Wr3, bl3, w, N, 64);
  agg_combine_norm64<<<aggBlocks64, blk, 0, stream>>>(z, w, row_ptr, csr,
                                                      (float*)d_out, N);
}

// Round 2
// 844.114 us; speedup vs baseline: 1.2773x; 1.2773x over previous
//
#include <hip/hip_runtime.h>

// ---------------------------------------------------------------------------
// 3-layer GraphSAGE (mean aggr, root weight) on MI355X, fp32.
//   per layer: out = mean_{j->i}(x_j) @ Wl + bl + x_i @ Wr   (+relu / +L2norm)
// Strategy:
//   - transform-first (mean is linear): z = h@Wl, w = h@Wr+b, out = agg(z)+w
//   - CSR build per call: deg count -> 3-kernel parallel scan -> scatter
//     (R1: single-block scan was 260us on one CU; now tiled multi-block)
//   - per-layer dual-GEMM fused into one dispatch (shared A tile reads)
// ---------------------------------------------------------------------------

#define SCAN_TILE 4096  // elems per tile; 256 thr x 16 consecutive elems each

// ------------------------- CSR build ---------------------------------------

__global__ void count_deg_kernel(const int* __restrict__ dst, int E,
                                 int* __restrict__ deg) {
  for (int i = blockIdx.x * blockDim.x + threadIdx.x; i < E;
       i += gridDim.x * blockDim.x)
    atomicAdd(&deg[dst[i]], 1);
}

// pass 1: per-tile sums (coalesced strided reads)
__global__ __launch_bounds__(256) void tile_sum_kernel(
    const int* __restrict__ deg, int N, int* __restrict__ tile_sums) {
  const int t = threadIdx.x;
  const int base = blockIdx.x * SCAN_TILE;
  int s = 0;
#pragma unroll
  for (int j = 0; j < SCAN_TILE / 256; ++j) {
    int idx = base + j * 256 + t;
    if (idx < N) s += deg[idx];
  }
  __shared__ int red[256];
  red[t] = s;
  __syncthreads();
  for (int d = 128; d > 0; d >>= 1) {
    if (t < d) red[t] += red[t + d];
    __syncthreads();
  }
  if (t == 0) tile_sums[blockIdx.x] = red[0];
}

// pass 2: single-block scan of tile sums (nTiles <= 256) + write row_ptr[N]
__global__ __launch_bounds__(256) void scan_tiles_kernel(
    const int* __restrict__ tile_sums, int nTiles,
    int* __restrict__ tile_offsets, int* __restrict__ row_ptr, int N) {
  __shared__ int sh[256];
  const int t = threadIdx.x;
  const int v = (t < nTiles) ? tile_sums[t] : 0;
  sh[t] = v;
  __syncthreads();
  for (int d = 1; d < 256; d <<= 1) {
    int u = (t >= d) ? sh[t - d] : 0;
    __syncthreads();
    sh[t] += u;
    __syncthreads();
  }
  if (t < nTiles) tile_offsets[t] = sh[t] - v;  // exclusive
  if (t == 255) row_ptr[N] = sh[255];           // total edge count
}

// pass 3: per-tile exclusive scan + writeback of row_ptr and cursor
__global__ __launch_bounds__(256) void tile_scan_kernel(
    const int* __restrict__ deg, const int* __restrict__ tile_offsets, int N,
    int* __restrict__ row_ptr, int* __restrict__ cursor) {
  const int t = threadIdx.x;
  const int base = blockIdx.x * SCAN_TILE + t * (SCAN_TILE / 256);
  int vals[SCAN_TILE / 256];
  int s = 0;
#pragma unroll
  for (int j = 0; j < SCAN_TILE / 256; ++j) {
    int idx = base + j;
    vals[j] = (idx < N) ? deg[idx] : 0;
    s += vals[j];
  }
  __shared__ int sh[256];
  sh[t] = s;
  __syncthreads();
  for (int d = 1; d < 256; d <<= 1) {
    int u = (t >= d) ? sh[t - d] : 0;
    __syncthreads();
    sh[t] += u;
    __syncthreads();
  }
  int running = tile_offsets[blockIdx.x] + sh[t] - s;  // excl prefix for chunk
#pragma unroll
  for (int j = 0; j < SCAN_TILE / 256; ++j) {
    int idx = base + j;
    if (idx < N) {
      row_ptr[idx] = running;
      cursor[idx] = running;
      running += vals[j];
    }
  }
}

__global__ void scatter_kernel(const int* __restrict__ src,
                               const int* __restrict__ dst, int E,
                               int* __restrict__ cursor, int* __restrict__ csr) {
  for (int i = blockIdx.x * blockDim.x + threadIdx.x; i < E;
       i += gridDim.x * blockDim.x) {
    int d = dst[i];
    int p = atomicAdd(&cursor[d], 1);
    csr[p] = src[i];
  }
}

// ------------------------- fused dual GEMM ----------------------------------
// C1[N x M] = A @ B1 ; C2[N x M] = A @ B2 + bias   (A is [N x 128])
// grid.x = 2*(M/64): first half -> B1/C1, second half -> B2/C2.
// Tile 128 rows x 64 cols per 256-thread block, K tiled by 32;
// per thread 4x8 micro-tile.

__global__ __launch_bounds__(256) void gemm_dual_k128(
    const float* __restrict__ A, const float* __restrict__ B1,
    const float* __restrict__ B2, const float* __restrict__ bias,
    float* __restrict__ C1, float* __restrict__ C2, int N, int M) {
  __shared__ float As[128][33];  // +1 pad: conflict-free column reads
  __shared__ float Bs[32][64];
  const int t = threadIdx.x;
  const int half = gridDim.x >> 1;
  int bx = blockIdx.x;
  const float* B;
  float* C;
  const float* bs;
  if (bx < half) {
    B = B1; C = C1; bs = nullptr;
  } else {
    B = B2; C = C2; bs = bias; bx -= half;
  }
  const int rb = blockIdx.y * 128;
  const int cb = bx * 64;
  const int ty = t >> 3;  // 0..31 -> 4-row group
  const int tx = t & 7;   // 0..7  -> 8-col group

  float acc[4][8];
#pragma unroll
  for (int r = 0; r < 4; ++r)
#pragma unroll
    for (int c = 0; c < 8; ++c) acc[r][c] = 0.f;

  for (int kt = 0; kt < 128; kt += 32) {
#pragma unroll
    for (int i = 0; i < 4; ++i) {
      int idx = t + i * 256;
      int lr = idx >> 3, k4 = idx & 7;
      int row = rb + lr;
      float4 v = make_float4(0.f, 0.f, 0.f, 0.f);
      if (row < N)
        v = *(const float4*)(A + (size_t)row * 128 + kt + k4 * 4);
      As[lr][k4 * 4 + 0] = v.x;
      As[lr][k4 * 4 + 1] = v.y;
      As[lr][k4 * 4 + 2] = v.z;
      As[lr][k4 * 4 + 3] = v.w;
    }
#pragma unroll
    for (int i = 0; i < 2; ++i) {
      int idx = t + i * 256;
      int kk = idx >> 4, c4 = idx & 15;
      float4 v = *(const float4*)(B + (size_t)(kt + kk) * M + cb + c4 * 4);
      *(float4*)(&Bs[kk][c4 * 4]) = v;
    }
    __syncthreads();
#pragma unroll
    for (int kk = 0; kk < 32; ++kk) {
      float a0 = As[ty * 4 + 0][kk];
      float a1 = As[ty * 4 + 1][kk];
      float a2 = As[ty * 4 + 2][kk];
      float a3 = As[ty * 4 + 3][kk];
      float4 b0 = *(const float4*)(&Bs[kk][tx * 8]);
      float4 b1 = *(const float4*)(&Bs[kk][tx * 8 + 4]);
      float bb[8] = {b0.x, b0.y, b0.z, b0.w, b1.x, b1.y, b1.z, b1.w};
#pragma unroll
      for (int c = 0; c < 8; ++c) {
        acc[0][c] = fmaf(a0, bb[c], acc[0][c]);
        acc[1][c] = fmaf(a1, bb[c], acc[1][c]);
        acc[2][c] = fmaf(a2, bb[c], acc[2][c]);
        acc[3][c] = fmaf(a3, bb[c], acc[3][c]);
      }
    }
    __syncthreads();
  }

  float bv[8];
#pragma unroll
  for (int c = 0; c < 8; ++c) bv[c] = bs ? bs[cb + tx * 8 + c] : 0.f;
#pragma unroll
  for (int r = 0; r < 4; ++r) {
    int row = rb + ty * 4 + r;
    if (row >= N) continue;
    float4 o0 = make_float4(acc[r][0] + bv[0], acc[r][1] + bv[1],
                            acc[r][2] + bv[2], acc[r][3] + bv[3]);
    float4 o1 = make_float4(acc[r][4] + bv[4], acc[r][5] + bv[5],
                            acc[r][6] + bv[6], acc[r][7] + bv[7]);
    float* cp = C + (size_t)row * M + cb + tx * 8;
    *(float4*)(cp) = o0;
    *(float4*)(cp + 4) = o1;
  }
}

// ------------------------- aggregation: out = relu(mean(z[nbrs]) + w) -------
// D=128: 32 lanes per node (float4/lane), 8 nodes per 256-thread block.

__global__ __launch_bounds__(256) void agg_combine_relu128(
    const float* __restrict__ z, const float* __restrict__ w,
    const int* __restrict__ row_ptr, const int* __restrict__ csr,
    float* __restrict__ out, int N) {
  const int g = threadIdx.x >> 5;
  const int lane = threadIdx.x & 31;
  const int node = blockIdx.x * 8 + g;
  if (node >= N) return;
  const int s = row_ptr[node];
  const int e = row_ptr[node + 1];
  float4 a0 = make_float4(0.f, 0.f, 0.f, 0.f);
  float4 a1 = make_float4(0.f, 0.f, 0.f, 0.f);
  int i = s;
  for (; i + 1 < e; i += 2) {
    int s0 = csr[i], s1 = csr[i + 1];
    float4 v0 = *(const float4*)(z + (size_t)s0 * 128 + lane * 4);
    float4 v1 = *(const float4*)(z + (size_t)s1 * 128 + lane * 4);
    a0.x += v0.x; a0.y += v0.y; a0.z += v0.z; a0.w += v0.w;
    a1.x += v1.x; a1.y += v1.y; a1.z += v1.z; a1.w += v1.w;
  }
  if (i < e) {
    int s0 = csr[i];
    float4 v0 = *(const float4*)(z + (size_t)s0 * 128 + lane * 4);
    a0.x += v0.x; a0.y += v0.y; a0.z += v0.z; a0.w += v0.w;
  }
  a0.x += a1.x; a0.y += a1.y; a0.z += a1.z; a0.w += a1.w;
  const int d = e - s;
  const float inv = 1.0f / (float)(d > 0 ? d : 1);
  float4 wv = *(const float4*)(w + (size_t)node * 128 + lane * 4);
  float4 o;
  o.x = fmaxf(fmaf(a0.x, inv, wv.x), 0.f);
  o.y = fmaxf(fmaf(a0.y, inv, wv.y), 0.f);
  o.z = fmaxf(fmaf(a0.z, inv, wv.z), 0.f);
  o.w = fmaxf(fmaf(a0.w, inv, wv.w), 0.f);
  *(float4*)(out + (size_t)node * 128 + lane * 4) = o;
}

// D=64 + row L2-normalize: 16 lanes per node, 16 nodes per block.
__global__ __launch_bounds__(256) void agg_combine_norm64(
    const float* __restrict__ z, const float* __restrict__ w,
    const int* __restrict__ row_ptr, const int* __restrict__ csr,
    float* __restrict__ out, int N) {
  const int g = threadIdx.x >> 4;
  const int lane = threadIdx.x & 15;
  const int node = blockIdx.x * 16 + g;
  if (node >= N) return;
  const int s = row_ptr[node];
  const int e = row_ptr[node + 1];
  float4 a0 = make_float4(0.f, 0.f, 0.f, 0.f);
  float4 a1 = make_float4(0.f, 0.f, 0.f, 0.f);
  int i = s;
  for (; i + 1 < e; i += 2) {
    int s0 = csr[i], s1 = csr[i + 1];
    float4 v0 = *(const float4*)(z + (size_t)s0 * 64 + lane * 4);
    float4 v1 = *(const float4*)(z + (size_t)s1 * 64 + lane * 4);
    a0.x += v0.x; a0.y += v0.y; a0.z += v0.z; a0.w += v0.w;
    a1.x += v1.x; a1.y += v1.y; a1.z += v1.z; a1.w += v1.w;
  }
  if (i < e) {
    int s0 = csr[i];
    float4 v0 = *(const float4*)(z + (size_t)s0 * 64 + lane * 4);
    a0.x += v0.x; a0.y += v0.y; a0.z += v0.z; a0.w += v0.w;
  }
  a0.x += a1.x; a0.y += a1.y; a0.z += a1.z; a0.w += a1.w;
  const int d = e - s;
  const float inv = 1.0f / (float)(d > 0 ? d : 1);
  float4 wv = *(const float4*)(w + (size_t)node * 64 + lane * 4);
  float4 v;
  v.x = fmaf(a0.x, inv, wv.x);
  v.y = fmaf(a0.y, inv, wv.y);
  v.z = fmaf(a0.z, inv, wv.z);
  v.w = fmaf(a0.w, inv, wv.w);
  float n2 = v.x * v.x + v.y * v.y + v.z * v.z + v.w * v.w;
  n2 += __shfl_xor(n2, 1);
  n2 += __shfl_xor(n2, 2);
  n2 += __shfl_xor(n2, 4);
  n2 += __shfl_xor(n2, 8);
  const float invn = 1.0f / fmaxf(sqrtf(n2), 1e-12f);
  v.x *= invn; v.y *= invn; v.z *= invn; v.w *= invn;
  *(float4*)(out + (size_t)node * 64 + lane * 4) = v;
}

// ------------------------- launch ------------------------------------------

extern "C" void kernel_launch(void* const* d_in, const int* in_sizes, int n_in,
                              void* d_out, int out_size, void* d_ws,
                              size_t ws_size, hipStream_t stream) {
  const float* x   = (const float*)d_in[0];
  const int*   ei  = (const int*)d_in[1];
  const float* Wl1 = (const float*)d_in[2];
  const float* bl1 = (const float*)d_in[3];
  const float* Wr1 = (const float*)d_in[4];
  const float* Wl2 = (const float*)d_in[5];
  const float* bl2 = (const float*)d_in[6];
  const float* Wr2 = (const float*)d_in[7];
  const float* Wl3 = (const float*)d_in[8];
  const float* bl3 = (const float*)d_in[9];
  const float* Wr3 = (const float*)d_in[10];

  const int N = in_sizes[0] / 128;
  const int E = in_sizes[1] / 2;
  const int* src = ei;       // edge_index[0]
  const int* dst = ei + E;   // edge_index[1]

  const int nTiles = (N + SCAN_TILE - 1) / SCAN_TILE;  // 25 for N=100k (<=256)

  char* ws = (char*)d_ws;
  size_t off = 0;
  auto take = [&](size_t bytes) -> char* {
    char* p = ws + off;
    off += (bytes + 255) & ~(size_t)255;
    return p;
  };
  float* h         = (float*)take((size_t)N * 128 * 4);
  float* z         = (float*)take((size_t)N * 128 * 4);
  float* w         = (float*)take((size_t)N * 128 * 4);
  int*   deg       = (int*)take((size_t)N * 4);
  int*   row_ptr   = (int*)take((size_t)(N + 1) * 4);
  int*   cursor    = (int*)take((size_t)N * 4);
  int*   csr       = (int*)take((size_t)E * 4);
  int*   tile_sums = (int*)take((size_t)256 * 4);
  int*   tile_offs = (int*)take((size_t)256 * 4);
  (void)ws_size;

  // --- CSR build
  hipMemsetAsync(deg, 0, (size_t)N * 4, stream);
  count_deg_kernel<<<2048, 256, 0, stream>>>(dst, E, deg);
  tile_sum_kernel<<<nTiles, 256, 0, stream>>>(deg, N, tile_sums);
  scan_tiles_kernel<<<1, 256, 0, stream>>>(tile_sums, nTiles, tile_offs,
                                           row_ptr, N);
  tile_scan_kernel<<<nTiles, 256, 0, stream>>>(deg, tile_offs, N, row_ptr,
                                               cursor);
  scatter_kernel<<<2048, 256, 0, stream>>>(src, dst, E, cursor, csr);

  const dim3 blk(256);
  const dim3 gd2(4, (N + 127) / 128);  // dual GEMM, M = 128 (2 col-tiles each)
  const dim3 gd1(2, (N + 127) / 128);  // dual GEMM, M = 64  (1 col-tile each)
  const int aggBlocks128 = (N + 7) / 8;
  const int aggBlocks64  = (N + 15) / 16;

  // --- layer 1: z = x@Wl1, w = x@Wr1+bl1, h = relu(mean-agg(z)+w)
  gemm_dual_k128<<<gd2, blk, 0, stream>>>(x, Wl1, Wr1, bl1, z, w, N, 128);
  agg_combine_relu128<<<aggBlocks128, blk, 0, stream>>>(z, w, row_ptr, csr, h, N);

  // --- layer 2
  gemm_dual_k128<<<gd2, blk, 0, stream>>>(h, Wl2, Wr2, bl2, z, w, N, 128);
  agg_combine_relu128<<<aggBlocks128, blk, 0, stream>>>(z, w, row_ptr, csr, h, N);

  // --- layer 3 (width 64) + L2 normalize
  gemm_dual_k128<<<gd1, blk, 0, stream>>>(h, Wl3, Wr3, bl3, z, w, N, 64);
  agg_combine_norm64<<<aggBlocks64, blk, 0, stream>>>(z, w, row_ptr, csr,
                                                      (float*)d_out, N);
}

// Round 3
// 721.251 us; speedup vs baseline: 1.4949x; 1.1703x over previous
//
#include <hip/hip_runtime.h>

// ---------------------------------------------------------------------------
// 3-layer GraphSAGE (mean aggr, root weight) on MI355X, fp32.
//   per layer: out = mean_{j->i}(x_j) @ Wl + bl + x_i @ Wr   (+relu / +L2norm)
// Strategy:
//   - transform-first (mean is linear): z = h@Wl, w = h@Wr+b, out = agg(z)+w
//   - bucketed two-phase CSR build (R2: global scatter had 16x write
//     amplification, 107MB for a 6.4MB csr; now LDS-staged partition into
//     512-node buckets + per-bucket LDS-cursor scatter)
//   - per-layer dual-GEMM fused into one dispatch
// ---------------------------------------------------------------------------

#define BSHIFT 9                 // 512 nodes per bucket
#define BNODES (1 << BSHIFT)
#define ROUND_LOG 12             // 4096 edges per partition round

// ------------------------- CSR build ---------------------------------------

// pass A1: bucket histogram (LDS-privatized)
__global__ __launch_bounds__(256) void hist_kernel(const int* __restrict__ dst,
                                                   int E,
                                                   int* __restrict__ gcnt) {
  __shared__ int h[256];
  h[threadIdx.x] = 0;
  __syncthreads();
  for (int i = blockIdx.x * 256 + threadIdx.x; i < E; i += gridDim.x * 256)
    atomicAdd(&h[dst[i] >> BSHIFT], 1);
  __syncthreads();
  int v = h[threadIdx.x];
  if (v) atomicAdd(&gcnt[threadIdx.x], v);
}

// pass A2: exclusive scan of bucket counts (NB <= 256) -> bases + cursors
__global__ __launch_bounds__(256) void bucket_scan_kernel(
    const int* __restrict__ gcnt, int NB, int* __restrict__ gbase,
    int* __restrict__ gcur, int* __restrict__ row_ptr, int N, int E) {
  __shared__ int sh[256];
  const int t = threadIdx.x;
  const int v = (t < NB) ? gcnt[t] : 0;
  sh[t] = v;
  __syncthreads();
  for (int d = 1; d < 256; d <<= 1) {
    int u = (t >= d) ? sh[t - d] : 0;
    __syncthreads();
    sh[t] += u;
    __syncthreads();
  }
  gbase[t] = sh[t] - v;
  gcur[t] = sh[t] - v;
  if (t == 0) row_ptr[N] = E;
}

// pass A3: partition edges into bucket-grouped (src,dst) pairs.
// Round-based: LDS count -> one global cursor atomic per bucket per round ->
// contiguous ~170B runs per bucket (write amp ~1.3x instead of 16x).
__global__ __launch_bounds__(256) void partition_kernel(
    const int* __restrict__ src, const int* __restrict__ dst, int E,
    int* __restrict__ gcur, int2* __restrict__ pairs) {
  __shared__ int lcnt[256];
  __shared__ int lbase[256];
  const int t = threadIdx.x;
  const int nRounds = (E + (1 << ROUND_LOG) - 1) >> ROUND_LOG;
  for (int r = blockIdx.x; r < nRounds; r += gridDim.x) {
    const int base = r << ROUND_LOG;
    lcnt[t] = 0;
    __syncthreads();
    int pk[16];  // (bucket << 12) | local_pos ; -1 = inactive
#pragma unroll
    for (int j = 0; j < 16; ++j) {
      int idx = base + j * 256 + t;
      pk[j] = -1;
      if (idx < E) {
        int b = dst[idx] >> BSHIFT;
        int lp = atomicAdd(&lcnt[b], 1);
        pk[j] = (b << 12) | lp;  // lp < 4096
      }
    }
    __syncthreads();
    int c = lcnt[t];
    if (c > 0) lbase[t] = atomicAdd(&gcur[t], c);
    __syncthreads();
#pragma unroll
    for (int j = 0; j < 16; ++j) {
      if (pk[j] >= 0) {
        int idx = base + j * 256 + t;
        int b = pk[j] >> 12;
        int p = lbase[b] + (pk[j] & 0xFFF);
        pairs[p] = make_int2(src[idx], dst[idx]);  // dst/src re-read: L1/L2 hit
      }
    }
    __syncthreads();
  }
}

// pass B: one workgroup per bucket. LDS degree count -> LDS scan -> row_ptr,
// then scatter srcs into the bucket's csr region via LDS-local cursors.
__global__ __launch_bounds__(256) void bucket_csr_kernel(
    const int2* __restrict__ pairs, const int* __restrict__ gbase,
    const int* __restrict__ gcnt, int N, int* __restrict__ row_ptr,
    int* __restrict__ csr) {
  const int b = blockIdx.x;
  const int t = threadIdx.x;
  const int nb0 = b << BSHIFT;
  __shared__ int ldeg[BNODES];
  __shared__ int lscan[256];
  __shared__ int lcur[BNODES];
  const int base = gbase[b];
  const int cnt = gcnt[b];
  ldeg[t] = 0;
  ldeg[t + 256] = 0;
  __syncthreads();
  for (int e = t; e < cnt; e += 256)
    atomicAdd(&ldeg[pairs[base + e].y - nb0], 1);
  __syncthreads();
  const int s2 = ldeg[2 * t] + ldeg[2 * t + 1];
  lscan[t] = s2;
  __syncthreads();
  for (int d = 1; d < 256; d <<= 1) {
    int u = (t >= d) ? lscan[t - d] : 0;
    __syncthreads();
    lscan[t] += u;
    __syncthreads();
  }
  const int ex = lscan[t] - s2;           // edges before node 2t (in bucket)
  const int o0 = base + ex;               // node 2t's csr start
  const int o1 = o0 + ldeg[2 * t];        // node 2t+1's csr start
  const int n0 = nb0 + 2 * t;
  if (n0 < N) row_ptr[n0] = o0;
  if (n0 + 1 < N) row_ptr[n0 + 1] = o1;
  lcur[2 * t] = o0;
  lcur[2 * t + 1] = o1;
  __syncthreads();
  for (int e = t; e < cnt; e += 256) {
    int2 p = pairs[base + e];
    int pos = atomicAdd(&lcur[p.y - nb0], 1);
    csr[pos] = p.x;  // random within a 32KB L2-hot region
  }
}

// ------------------------- fused dual GEMM ----------------------------------
// C1[N x M] = A @ B1 ; C2[N x M] = A @ B2 + bias   (A is [N x 128])
// grid.x = 2*(M/64): first half -> B1/C1, second half -> B2/C2.
// Tile 128 rows x 64 cols per 256-thread block, K tiled by 32;
// per thread 4x8 micro-tile.

__global__ __launch_bounds__(256) void gemm_dual_k128(
    const float* __restrict__ A, const float* __restrict__ B1,
    const float* __restrict__ B2, const float* __restrict__ bias,
    float* __restrict__ C1, float* __restrict__ C2, int N, int M) {
  __shared__ float As[128][33];  // +1 pad: conflict-free column reads
  __shared__ float Bs[32][64];
  const int t = threadIdx.x;
  const int half = gridDim.x >> 1;
  int bx = blockIdx.x;
  const float* B;
  float* C;
  const float* bs;
  if (bx < half) {
    B = B1; C = C1; bs = nullptr;
  } else {
    B = B2; C = C2; bs = bias; bx -= half;
  }
  const int rb = blockIdx.y * 128;
  const int cb = bx * 64;
  const int ty = t >> 3;  // 0..31 -> 4-row group
  const int tx = t & 7;   // 0..7  -> 8-col group

  float acc[4][8];
#pragma unroll
  for (int r = 0; r < 4; ++r)
#pragma unroll
    for (int c = 0; c < 8; ++c) acc[r][c] = 0.f;

  for (int kt = 0; kt < 128; kt += 32) {
#pragma unroll
    for (int i = 0; i < 4; ++i) {
      int idx = t + i * 256;
      int lr = idx >> 3, k4 = idx & 7;
      int row = rb + lr;
      float4 v = make_float4(0.f, 0.f, 0.f, 0.f);
      if (row < N)
        v = *(const float4*)(A + (size_t)row * 128 + kt + k4 * 4);
      As[lr][k4 * 4 + 0] = v.x;
      As[lr][k4 * 4 + 1] = v.y;
      As[lr][k4 * 4 + 2] = v.z;
      As[lr][k4 * 4 + 3] = v.w;
    }
#pragma unroll
    for (int i = 0; i < 2; ++i) {
      int idx = t + i * 256;
      int kk = idx >> 4, c4 = idx & 15;
      float4 v = *(const float4*)(B + (size_t)(kt + kk) * M + cb + c4 * 4);
      *(float4*)(&Bs[kk][c4 * 4]) = v;
    }
    __syncthreads();
#pragma unroll
    for (int kk = 0; kk < 32; ++kk) {
      float a0 = As[ty * 4 + 0][kk];
      float a1 = As[ty * 4 + 1][kk];
      float a2 = As[ty * 4 + 2][kk];
      float a3 = As[ty * 4 + 3][kk];
      float4 b0 = *(const float4*)(&Bs[kk][tx * 8]);
      float4 b1 = *(const float4*)(&Bs[kk][tx * 8 + 4]);
      float bb[8] = {b0.x, b0.y, b0.z, b0.w, b1.x, b1.y, b1.z, b1.w};
#pragma unroll
      for (int c = 0; c < 8; ++c) {
        acc[0][c] = fmaf(a0, bb[c], acc[0][c]);
        acc[1][c] = fmaf(a1, bb[c], acc[1][c]);
        acc[2][c] = fmaf(a2, bb[c], acc[2][c]);
        acc[3][c] = fmaf(a3, bb[c], acc[3][c]);
      }
    }
    __syncthreads();
  }

  float bv[8];
#pragma unroll
  for (int c = 0; c < 8; ++c) bv[c] = bs ? bs[cb + tx * 8 + c] : 0.f;
#pragma unroll
  for (int r = 0; r < 4; ++r) {
    int row = rb + ty * 4 + r;
    if (row >= N) continue;
    float4 o0 = make_float4(acc[r][0] + bv[0], acc[r][1] + bv[1],
                            acc[r][2] + bv[2], acc[r][3] + bv[3]);
    float4 o1 = make_float4(acc[r][4] + bv[4], acc[r][5] + bv[5],
                            acc[r][6] + bv[6], acc[r][7] + bv[7]);
    float* cp = C + (size_t)row * M + cb + tx * 8;
    *(float4*)(cp) = o0;
    *(float4*)(cp + 4) = o1;
  }
}

// ------------------------- aggregation: out = relu(mean(z[nbrs]) + w) -------
// D=128: 32 lanes per node (float4/lane), 8 nodes per 256-thread block.

__global__ __launch_bounds__(256) void agg_combine_relu128(
    const float* __restrict__ z, const float* __restrict__ w,
    const int* __restrict__ row_ptr, const int* __restrict__ csr,
    float* __restrict__ out, int N) {
  const int g = threadIdx.x >> 5;
  const int lane = threadIdx.x & 31;
  const int node = blockIdx.x * 8 + g;
  if (node >= N) return;
  const int s = row_ptr[node];
  const int e = row_ptr[node + 1];
  float4 a0 = make_float4(0.f, 0.f, 0.f, 0.f);
  float4 a1 = make_float4(0.f, 0.f, 0.f, 0.f);
  int i = s;
  for (; i + 1 < e; i += 2) {
    int s0 = csr[i], s1 = csr[i + 1];
    float4 v0 = *(const float4*)(z + (size_t)s0 * 128 + lane * 4);
    float4 v1 = *(const float4*)(z + (size_t)s1 * 128 + lane * 4);
    a0.x += v0.x; a0.y += v0.y; a0.z += v0.z; a0.w += v0.w;
    a1.x += v1.x; a1.y += v1.y; a1.z += v1.z; a1.w += v1.w;
  }
  if (i < e) {
    int s0 = csr[i];
    float4 v0 = *(const float4*)(z + (size_t)s0 * 128 + lane * 4);
    a0.x += v0.x; a0.y += v0.y; a0.z += v0.z; a0.w += v0.w;
  }
  a0.x += a1.x; a0.y += a1.y; a0.z += a1.z; a0.w += a1.w;
  const int d = e - s;
  const float inv = 1.0f / (float)(d > 0 ? d : 1);
  float4 wv = *(const float4*)(w + (size_t)node * 128 + lane * 4);
  float4 o;
  o.x = fmaxf(fmaf(a0.x, inv, wv.x), 0.f);
  o.y = fmaxf(fmaf(a0.y, inv, wv.y), 0.f);
  o.z = fmaxf(fmaf(a0.z, inv, wv.z), 0.f);
  o.w = fmaxf(fmaf(a0.w, inv, wv.w), 0.f);
  *(float4*)(out + (size_t)node * 128 + lane * 4) = o;
}

// D=64 + row L2-normalize: 16 lanes per node, 16 nodes per block.
__global__ __launch_bounds__(256) void agg_combine_norm64(
    const float* __restrict__ z, const float* __restrict__ w,
    const int* __restrict__ row_ptr, const int* __restrict__ csr,
    float* __restrict__ out, int N) {
  const int g = threadIdx.x >> 4;
  const int lane = threadIdx.x & 15;
  const int node = blockIdx.x * 16 + g;
  if (node >= N) return;
  const int s = row_ptr[node];
  const int e = row_ptr[node + 1];
  float4 a0 = make_float4(0.f, 0.f, 0.f, 0.f);
  float4 a1 = make_float4(0.f, 0.f, 0.f, 0.f);
  int i = s;
  for (; i + 1 < e; i += 2) {
    int s0 = csr[i], s1 = csr[i + 1];
    float4 v0 = *(const float4*)(z + (size_t)s0 * 64 + lane * 4);
    float4 v1 = *(const float4*)(z + (size_t)s1 * 64 + lane * 4);
    a0.x += v0.x; a0.y += v0.y; a0.z += v0.z; a0.w += v0.w;
    a1.x += v1.x; a1.y += v1.y; a1.z += v1.z; a1.w += v1.w;
  }
  if (i < e) {
    int s0 = csr[i];
    float4 v0 = *(const float4*)(z + (size_t)s0 * 64 + lane * 4);
    a0.x += v0.x; a0.y += v0.y; a0.z += v0.z; a0.w += v0.w;
  }
  a0.x += a1.x; a0.y += a1.y; a0.z += a1.z; a0.w += a1.w;
  const int d = e - s;
  const float inv = 1.0f / (float)(d > 0 ? d : 1);
  float4 wv = *(const float4*)(w + (size_t)node * 64 + lane * 4);
  float4 v;
  v.x = fmaf(a0.x, inv, wv.x);
  v.y = fmaf(a0.y, inv, wv.y);
  v.z = fmaf(a0.z, inv, wv.z);
  v.w = fmaf(a0.w, inv, wv.w);
  float n2 = v.x * v.x + v.y * v.y + v.z * v.z + v.w * v.w;
  n2 += __shfl_xor(n2, 1);
  n2 += __shfl_xor(n2, 2);
  n2 += __shfl_xor(n2, 4);
  n2 += __shfl_xor(n2, 8);
  const float invn = 1.0f / fmaxf(sqrtf(n2), 1e-12f);
  v.x *= invn; v.y *= invn; v.z *= invn; v.w *= invn;
  *(float4*)(out + (size_t)node * 64 + lane * 4) = v;
}

// ------------------------- launch ------------------------------------------

extern "C" void kernel_launch(void* const* d_in, const int* in_sizes, int n_in,
                              void* d_out, int out_size, void* d_ws,
                              size_t ws_size, hipStream_t stream) {
  const float* x   = (const float*)d_in[0];
  const int*   ei  = (const int*)d_in[1];
  const float* Wl1 = (const float*)d_in[2];
  const float* bl1 = (const float*)d_in[3];
  const float* Wr1 = (const float*)d_in[4];
  const float* Wl2 = (const float*)d_in[5];
  const float* bl2 = (const float*)d_in[6];
  const float* Wr2 = (const float*)d_in[7];
  const float* Wl3 = (const float*)d_in[8];
  const float* bl3 = (const float*)d_in[9];
  const float* Wr3 = (const float*)d_in[10];

  const int N = in_sizes[0] / 128;
  const int E = in_sizes[1] / 2;
  const int* src = ei;       // edge_index[0]
  const int* dst = ei + E;   // edge_index[1]

  const int NB = (N + BNODES - 1) >> BSHIFT;  // 196 for N=100k (<=256)

  char* ws = (char*)d_ws;
  size_t off = 0;
  auto take = [&](size_t bytes) -> char* {
    char* p = ws + off;
    off += (bytes + 255) & ~(size_t)255;
    return p;
  };
  float* h       = (float*)take((size_t)N * 128 * 4);
  float* z       = (float*)take((size_t)N * 128 * 4);
  float* w       = (float*)take((size_t)N * 128 * 4);
  int*   row_ptr = (int*)take((size_t)(N + 1) * 4);
  int*   csr     = (int*)take((size_t)E * 4);
  int2*  pairs   = (int2*)take((size_t)E * 8);
  int*   gcnt    = (int*)take((size_t)256 * 4);
  int*   gbase   = (int*)take((size_t)256 * 4);
  int*   gcur    = (int*)take((size_t)256 * 4);
  (void)ws_size;

  // --- CSR build (bucketed two-phase)
  hipMemsetAsync(gcnt, 0, 256 * 4, stream);
  hist_kernel<<<1024, 256, 0, stream>>>(dst, E, gcnt);
  bucket_scan_kernel<<<1, 256, 0, stream>>>(gcnt, NB, gbase, gcur, row_ptr, N,
                                            E);
  const int nRounds = (E + (1 << ROUND_LOG) - 1) >> ROUND_LOG;
  partition_kernel<<<nRounds, 256, 0, stream>>>(src, dst, E, gcur, pairs);
  bucket_csr_kernel<<<NB, 256, 0, stream>>>(pairs, gbase, gcnt, N, row_ptr,
                                            csr);

  const dim3 blk(256);
  const dim3 gd2(4, (N + 127) / 128);  // dual GEMM, M = 128 (2 col-tiles each)
  const dim3 gd1(2, (N + 127) / 128);  // dual GEMM, M = 64  (1 col-tile each)
  const int aggBlocks128 = (N + 7) / 8;
  const int aggBlocks64  = (N + 15) / 16;

  // --- layer 1: z = x@Wl1, w = x@Wr1+bl1, h = relu(mean-agg(z)+w)
  gemm_dual_k128<<<gd2, blk, 0, stream>>>(x, Wl1, Wr1, bl1, z, w, N, 128);
  agg_combine_relu128<<<aggBlocks128, blk, 0, stream>>>(z, w, row_ptr, csr, h, N);

  // --- layer 2
  gemm_dual_k128<<<gd2, blk, 0, stream>>>(h, Wl2, Wr2, bl2, z, w, N, 128);
  agg_combine_relu128<<<aggBlocks128, blk, 0, stream>>>(z, w, row_ptr, csr, h, N);

  // --- layer 3 (width 64) + L2 normalize
  gemm_dual_k128<<<gd1, blk, 0, stream>>>(h, Wl3, Wr3, bl3, z, w, N, 64);
  agg_combine_norm64<<<aggBlocks64, blk, 0, stream>>>(z, w, row_ptr, csr,
                                                      (float*)d_out, N);
}

// Round 4
// 458.246 us; speedup vs baseline: 2.3529x; 1.5739x over previous
//
#include <hip/hip_runtime.h>

// ---------------------------------------------------------------------------
// 3-layer GraphSAGE (mean aggr, root weight) on MI355X.
//   per layer: out = mean_{j->i}(x_j) @ Wl + bl + x_i @ Wr   (+relu / +L2norm)
// R4: internal bf16 (fp32 accum). MFMA GEMMs (16x16x32_bf16, B^T operand),
//     bf16 gather halves the 402MB/dispatch L2-miss traffic seen in R3.
// ---------------------------------------------------------------------------

#define BSHIFT 9                 // 512 nodes per bucket
#define BNODES (1 << BSHIFT)
#define ROUND_LOG 12             // 4096 edges per partition round

typedef __attribute__((ext_vector_type(8))) short bf16x8;
typedef __attribute__((ext_vector_type(4))) float f32x4;
typedef __attribute__((ext_vector_type(8))) unsigned short u16x8;

__device__ inline float bf2f(unsigned short u) {
  unsigned v = ((unsigned)u) << 16;
  return __builtin_bit_cast(float, v);
}
__device__ inline unsigned short f2bf(float f) {
  unsigned u = __builtin_bit_cast(unsigned, f);
  u += 0x7FFF + ((u >> 16) & 1);  // round-to-nearest-even
  return (unsigned short)(u >> 16);
}

// ------------------------- casts -------------------------------------------

__global__ __launch_bounds__(256) void cast_x_kernel(
    const float* __restrict__ in, unsigned short* __restrict__ out, int n8) {
  for (int i = blockIdx.x * 256 + threadIdx.x; i < n8; i += gridDim.x * 256) {
    float4 a = *(const float4*)(in + (size_t)i * 8);
    float4 b = *(const float4*)(in + (size_t)i * 8 + 4);
    u16x8 o;
    o[0] = f2bf(a.x); o[1] = f2bf(a.y); o[2] = f2bf(a.z); o[3] = f2bf(a.w);
    o[4] = f2bf(b.x); o[5] = f2bf(b.y); o[6] = f2bf(b.z); o[7] = f2bf(b.w);
    *(u16x8*)(out + (size_t)i * 8) = o;
  }
}

// W[K][M] fp32 -> WT[M][K] bf16
__global__ __launch_bounds__(256) void wtcast_kernel(
    const float* __restrict__ W, unsigned short* __restrict__ WT, int K,
    int M) {
  for (int i = blockIdx.x * 256 + threadIdx.x; i < K * M;
       i += gridDim.x * 256) {
    int k = i / M, m = i - k * M;
    WT[(size_t)m * K + k] = f2bf(W[i]);
  }
}

// ------------------------- CSR build ---------------------------------------

__global__ __launch_bounds__(256) void hist_kernel(const int* __restrict__ dst,
                                                   int E,
                                                   int* __restrict__ gcnt) {
  __shared__ int h[256];
  h[threadIdx.x] = 0;
  __syncthreads();
  for (int i = blockIdx.x * 256 + threadIdx.x; i < E; i += gridDim.x * 256)
    atomicAdd(&h[dst[i] >> BSHIFT], 1);
  __syncthreads();
  int v = h[threadIdx.x];
  if (v) atomicAdd(&gcnt[threadIdx.x], v);
}

__global__ __launch_bounds__(256) void bucket_scan_kernel(
    const int* __restrict__ gcnt, int NB, int* __restrict__ gbase,
    int* __restrict__ gcur, int* __restrict__ row_ptr, int N, int E) {
  __shared__ int sh[256];
  const int t = threadIdx.x;
  const int v = (t < NB) ? gcnt[t] : 0;
  sh[t] = v;
  __syncthreads();
  for (int d = 1; d < 256; d <<= 1) {
    int u = (t >= d) ? sh[t - d] : 0;
    __syncthreads();
    sh[t] += u;
    __syncthreads();
  }
  gbase[t] = sh[t] - v;
  gcur[t] = sh[t] - v;
  if (t == 0) row_ptr[N] = E;
}

// partition edges into bucket-grouped packed (local_dst<<17 | src) words
__global__ __launch_bounds__(256) void partition_kernel(
    const int* __restrict__ src, const int* __restrict__ dst, int E,
    int* __restrict__ gcur, unsigned int* __restrict__ pairs) {
  __shared__ int lcnt[256];
  __shared__ int lbase[256];
  const int t = threadIdx.x;
  const int nRounds = (E + (1 << ROUND_LOG) - 1) >> ROUND_LOG;
  for (int r = blockIdx.x; r < nRounds; r += gridDim.x) {
    const int base = r << ROUND_LOG;
    lcnt[t] = 0;
    __syncthreads();
    int pk[16];  // (bucket << 12) | local_pos ; -1 = inactive
#pragma unroll
    for (int j = 0; j < 16; ++j) {
      int idx = base + j * 256 + t;
      pk[j] = -1;
      if (idx < E) {
        int b = dst[idx] >> BSHIFT;
        int lp = atomicAdd(&lcnt[b], 1);
        pk[j] = (b << 12) | lp;
      }
    }
    __syncthreads();
    int c = lcnt[t];
    if (c > 0) lbase[t] = atomicAdd(&gcur[t], c);
    __syncthreads();
#pragma unroll
    for (int j = 0; j < 16; ++j) {
      if (pk[j] >= 0) {
        int idx = base + j * 256 + t;
        int b = pk[j] >> 12;
        int p = lbase[b] + (pk[j] & 0xFFF);
        pairs[p] = ((unsigned)(dst[idx] & (BNODES - 1)) << 17) |
                   (unsigned)src[idx];
      }
    }
    __syncthreads();
  }
}

__global__ __launch_bounds__(256) void bucket_csr_kernel(
    const unsigned int* __restrict__ pairs, const int* __restrict__ gbase,
    const int* __restrict__ gcnt, int N, int* __restrict__ row_ptr,
    int* __restrict__ csr) {
  const int b = blockIdx.x;
  const int t = threadIdx.x;
  const int nb0 = b << BSHIFT;
  __shared__ int ldeg[BNODES];
  __shared__ int lscan[256];
  __shared__ int lcur[BNODES];
  const int base = gbase[b];
  const int cnt = gcnt[b];
  ldeg[t] = 0;
  ldeg[t + 256] = 0;
  __syncthreads();
  for (int e = t; e < cnt; e += 256)
    atomicAdd(&ldeg[pairs[base + e] >> 17], 1);
  __syncthreads();
  const int s2 = ldeg[2 * t] + ldeg[2 * t + 1];
  lscan[t] = s2;
  __syncthreads();
  for (int d = 1; d < 256; d <<= 1) {
    int u = (t >= d) ? lscan[t - d] : 0;
    __syncthreads();
    lscan[t] += u;
    __syncthreads();
  }
  const int ex = lscan[t] - s2;
  const int o0 = base + ex;
  const int o1 = o0 + ldeg[2 * t];
  const int n0 = nb0 + 2 * t;
  if (n0 < N) row_ptr[n0] = o0;
  if (n0 + 1 < N) row_ptr[n0 + 1] = o1;
  lcur[2 * t] = o0;
  lcur[2 * t + 1] = o1;
  __syncthreads();
  for (int e = t; e < cnt; e += 256) {
    unsigned int p = pairs[base + e];
    int pos = atomicAdd(&lcur[p >> 17], 1);
    csr[pos] = (int)(p & 0x1FFFF);
  }
}

// ------------------------- MFMA dual GEMM -----------------------------------
// C1[N x M] = A @ B1 ; C2[N x M] = A @ B2 + bias.  A: [N][128] bf16 row-major,
// BT: [M][128] bf16 (pre-transposed weights; K contiguous -> symmetric frags).
// Block: 256 thr = 4 waves (2x2), tile 128 rows x 64 cols, BK=64.
// Wave: 64x32 output = 4x2 frags of 16x16, mfma_f32_16x16x32_bf16.

__global__ __launch_bounds__(256) void gemm_dual_bf16(
    const unsigned short* __restrict__ A, const unsigned short* __restrict__ BT1,
    const unsigned short* __restrict__ BT2, const float* __restrict__ bias,
    unsigned short* __restrict__ C1, unsigned short* __restrict__ C2, int N,
    int M) {
  __shared__ unsigned short As[128][72];  // +8 pad: 2-way-max LDS banks
  __shared__ unsigned short Bs[64][72];
  const int t = threadIdx.x;
  const int half = gridDim.x >> 1;
  int bx = blockIdx.x;
  const unsigned short* BT;
  unsigned short* C;
  const float* bs;
  if (bx < half) {
    BT = BT1; C = C1; bs = nullptr;
  } else {
    BT = BT2; C = C2; bs = bias; bx -= half;
  }
  const int rb = blockIdx.y * 128;
  const int cb = bx * 64;
  const int l = t & 63, wv = t >> 6;
  const int wr = wv >> 1, wc = wv & 1;   // 2x2 wave grid
  const int lr = l & 15, kb = l >> 4;    // frag row/col and k-block

  f32x4 acc[4][2];
#pragma unroll
  for (int fr = 0; fr < 4; ++fr)
#pragma unroll
    for (int fc = 0; fc < 2; ++fc) acc[fr][fc] = (f32x4)(0.f);

  const int sr = t >> 3;        // staging row 0..31
  const int sc = (t & 7) * 8;   // staging col (elems)

  for (int kt = 0; kt < 128; kt += 64) {
#pragma unroll
    for (int i = 0; i < 4; ++i) {  // A tile: 128 rows x 64 k
      int r = i * 32 + sr;
      int grow = rb + r;
      uint4 v = make_uint4(0, 0, 0, 0);
      if (grow < N) v = *(const uint4*)(A + (size_t)grow * 128 + kt + sc);
      *(uint4*)&As[r][sc] = v;
    }
#pragma unroll
    for (int i = 0; i < 2; ++i) {  // B tile: 64 outcols x 64 k
      int r = i * 32 + sr;
      uint4 v = *(const uint4*)(BT + (size_t)(cb + r) * 128 + kt + sc);
      *(uint4*)&Bs[r][sc] = v;
    }
    __syncthreads();
#pragma unroll
    for (int ks = 0; ks < 2; ++ks) {
      bf16x8 a[4], b[2];
#pragma unroll
      for (int fr = 0; fr < 4; ++fr)
        a[fr] = *(const bf16x8*)&As[wr * 64 + fr * 16 + lr][ks * 32 + kb * 8];
#pragma unroll
      for (int fc = 0; fc < 2; ++fc)
        b[fc] = *(const bf16x8*)&Bs[wc * 32 + fc * 16 + lr][ks * 32 + kb * 8];
#pragma unroll
      for (int fr = 0; fr < 4; ++fr)
#pragma unroll
        for (int fc = 0; fc < 2; ++fc)
          acc[fr][fc] = __builtin_amdgcn_mfma_f32_16x16x32_bf16(
              a[fr], b[fc], acc[fr][fc], 0, 0, 0);
    }
    __syncthreads();
  }
  // epilogue: C/D map col=lane&15, row=(lane>>4)*4+reg  [m89]
#pragma unroll
  for (int fc = 0; fc < 2; ++fc) {
    int col = cb + wc * 32 + fc * 16 + lr;
    float bv = bs ? bs[col] : 0.f;
#pragma unroll
    for (int fr = 0; fr < 4; ++fr) {
      int row0 = rb + wr * 64 + fr * 16 + kb * 4;
#pragma unroll
      for (int j = 0; j < 4; ++j) {
        int row = row0 + j;
        if (row < N) C[(size_t)row * M + col] = f2bf(acc[fr][fc][j] + bv);
      }
    }
  }
}

// ------------------------- aggregation (bf16) -------------------------------
// D=128: 16 lanes/node x 16B (8 bf16), 16 nodes per 256-thread block.

__global__ __launch_bounds__(256) void agg_relu_bf16_128(
    const unsigned short* __restrict__ z, const unsigned short* __restrict__ w,
    const int* __restrict__ row_ptr, const int* __restrict__ csr,
    unsigned short* __restrict__ out, int N) {
  const int g = threadIdx.x >> 4;
  const int lane = threadIdx.x & 15;
  const int node = blockIdx.x * 16 + g;
  if (node >= N) return;
  const int s = row_ptr[node];
  const int e = row_ptr[node + 1];
  float a0[8] = {0, 0, 0, 0, 0, 0, 0, 0};
  float a1[8] = {0, 0, 0, 0, 0, 0, 0, 0};
  int i = s;
  for (; i + 1 < e; i += 2) {
    u16x8 v0 = *(const u16x8*)(z + (size_t)csr[i] * 128 + lane * 8);
    u16x8 v1 = *(const u16x8*)(z + (size_t)csr[i + 1] * 128 + lane * 8);
#pragma unroll
    for (int j = 0; j < 8; ++j) {
      a0[j] += bf2f(v0[j]);
      a1[j] += bf2f(v1[j]);
    }
  }
  if (i < e) {
    u16x8 v0 = *(const u16x8*)(z + (size_t)csr[i] * 128 + lane * 8);
#pragma unroll
    for (int j = 0; j < 8; ++j) a0[j] += bf2f(v0[j]);
  }
  const int d = e - s;
  const float inv = 1.0f / (float)(d > 0 ? d : 1);
  u16x8 wv = *(const u16x8*)(w + (size_t)node * 128 + lane * 8);
  u16x8 o;
#pragma unroll
  for (int j = 0; j < 8; ++j)
    o[j] = f2bf(fmaxf(fmaf(a0[j] + a1[j], inv, bf2f(wv[j])), 0.f));
  *(u16x8*)(out + (size_t)node * 128 + lane * 8) = o;
}

// D=64 + L2 normalize: 8 lanes/node, 32 nodes/block, fp32 output.
__global__ __launch_bounds__(256) void agg_norm_bf16_64(
    const unsigned short* __restrict__ z, const unsigned short* __restrict__ w,
    const int* __restrict__ row_ptr, const int* __restrict__ csr,
    float* __restrict__ out, int N) {
  const int g = threadIdx.x >> 3;
  const int lane = threadIdx.x & 7;
  const int node = blockIdx.x * 32 + g;
  if (node >= N) return;
  const int s = row_ptr[node];
  const int e = row_ptr[node + 1];
  float a0[8] = {0, 0, 0, 0, 0, 0, 0, 0};
  float a1[8] = {0, 0, 0, 0, 0, 0, 0, 0};
  int i = s;
  for (; i + 1 < e; i += 2) {
    u16x8 v0 = *(const u16x8*)(z + (size_t)csr[i] * 64 + lane * 8);
    u16x8 v1 = *(const u16x8*)(z + (size_t)csr[i + 1] * 64 + lane * 8);
#pragma unroll
    for (int j = 0; j < 8; ++j) {
      a0[j] += bf2f(v0[j]);
      a1[j] += bf2f(v1[j]);
    }
  }
  if (i < e) {
    u16x8 v0 = *(const u16x8*)(z + (size_t)csr[i] * 64 + lane * 8);
#pragma unroll
    for (int j = 0; j < 8; ++j) a0[j] += bf2f(v0[j]);
  }
  const int d = e - s;
  const float inv = 1.0f / (float)(d > 0 ? d : 1);
  u16x8 wv = *(const u16x8*)(w + (size_t)node * 64 + lane * 8);
  float v[8];
  float n2 = 0.f;
#pragma unroll
  for (int j = 0; j < 8; ++j) {
    v[j] = fmaf(a0[j] + a1[j], inv, bf2f(wv[j]));
    n2 = fmaf(v[j], v[j], n2);
  }
  n2 += __shfl_xor(n2, 1);
  n2 += __shfl_xor(n2, 2);
  n2 += __shfl_xor(n2, 4);
  const float invn = 1.0f / fmaxf(sqrtf(n2), 1e-12f);
  float* op = out + (size_t)node * 64 + lane * 8;
  float4 o0 = make_float4(v[0] * invn, v[1] * invn, v[2] * invn, v[3] * invn);
  float4 o1 = make_float4(v[4] * invn, v[5] * invn, v[6] * invn, v[7] * invn);
  *(float4*)op = o0;
  *(float4*)(op + 4) = o1;
}

// ------------------------- launch ------------------------------------------

extern "C" void kernel_launch(void* const* d_in, const int* in_sizes, int n_in,
                              void* d_out, int out_size, void* d_ws,
                              size_t ws_size, hipStream_t stream) {
  const float* x   = (const float*)d_in[0];
  const int*   ei  = (const int*)d_in[1];
  const float* Wl1 = (const float*)d_in[2];
  const float* bl1 = (const float*)d_in[3];
  const float* Wr1 = (const float*)d_in[4];
  const float* Wl2 = (const float*)d_in[5];
  const float* bl2 = (const float*)d_in[6];
  const float* Wr2 = (const float*)d_in[7];
  const float* Wl3 = (const float*)d_in[8];
  const float* bl3 = (const float*)d_in[9];
  const float* Wr3 = (const float*)d_in[10];

  const int N = in_sizes[0] / 128;
  const int E = in_sizes[1] / 2;
  const int* src = ei;
  const int* dst = ei + E;
  const int NB = (N + BNODES - 1) >> BSHIFT;

  char* ws = (char*)d_ws;
  size_t off = 0;
  auto take = [&](size_t bytes) -> char* {
    char* p = ws + off;
    off += (bytes + 255) & ~(size_t)255;
    return p;
  };
  unsigned short* xb   = (unsigned short*)take((size_t)N * 128 * 2);
  unsigned short* h    = (unsigned short*)take((size_t)N * 128 * 2);
  unsigned short* z    = (unsigned short*)take((size_t)N * 128 * 2);
  unsigned short* w    = (unsigned short*)take((size_t)N * 128 * 2);
  unsigned short* WT[6];
  for (int i = 0; i < 6; ++i) WT[i] = (unsigned short*)take(128 * 128 * 2);
  int*          row_ptr = (int*)take((size_t)(N + 1) * 4);
  int*          csr     = (int*)take((size_t)E * 4);
  unsigned int* pairs   = (unsigned int*)take((size_t)E * 4);
  int*          gcnt    = (int*)take(256 * 4);
  int*          gbase   = (int*)take(256 * 4);
  int*          gcur    = (int*)take(256 * 4);
  (void)ws_size;

  // --- CSR build (bucketed two-phase, packed pairs)
  hipMemsetAsync(gcnt, 0, 256 * 4, stream);
  hist_kernel<<<1024, 256, 0, stream>>>(dst, E, gcnt);
  bucket_scan_kernel<<<1, 256, 0, stream>>>(gcnt, NB, gbase, gcur, row_ptr, N, E);
  const int nRounds = (E + (1 << ROUND_LOG) - 1) >> ROUND_LOG;
  partition_kernel<<<nRounds, 256, 0, stream>>>(src, dst, E, gcur, pairs);
  bucket_csr_kernel<<<NB, 256, 0, stream>>>(pairs, gbase, gcnt, N, row_ptr, csr);

  // --- casts
  cast_x_kernel<<<2048, 256, 0, stream>>>(x, xb, N * 16);
  wtcast_kernel<<<64, 256, 0, stream>>>(Wl1, WT[0], 128, 128);
  wtcast_kernel<<<64, 256, 0, stream>>>(Wr1, WT[1], 128, 128);
  wtcast_kernel<<<64, 256, 0, stream>>>(Wl2, WT[2], 128, 128);
  wtcast_kernel<<<64, 256, 0, stream>>>(Wr2, WT[3], 128, 128);
  wtcast_kernel<<<32, 256, 0, stream>>>(Wl3, WT[4], 128, 64);
  wtcast_kernel<<<32, 256, 0, stream>>>(Wr3, WT[5], 128, 64);

  const dim3 blk(256);
  const int rowBlocks = (N + 127) / 128;
  const dim3 gd2(4, rowBlocks);  // M=128: 2 col-tiles x 2 matrices
  const dim3 gd1(2, rowBlocks);  // M=64
  const int aggB128 = (N + 15) / 16;
  const int aggB64  = (N + 31) / 32;

  // --- layer 1
  gemm_dual_bf16<<<gd2, blk, 0, stream>>>(xb, WT[0], WT[1], bl1, z, w, N, 128);
  agg_relu_bf16_128<<<aggB128, blk, 0, stream>>>(z, w, row_ptr, csr, h, N);
  // --- layer 2
  gemm_dual_bf16<<<gd2, blk, 0, stream>>>(h, WT[2], WT[3], bl2, z, w, N, 128);
  agg_relu_bf16_128<<<aggB128, blk, 0, stream>>>(z, w, row_ptr, csr, h, N);
  // --- layer 3 (width 64) + L2 normalize
  gemm_dual_bf16<<<gd1, blk, 0, stream>>>(h, WT[4], WT[5], bl3, z, w, N, 64);
  agg_norm_bf16_64<<<aggB64, blk, 0, stream>>>(z, w, row_ptr, csr,
                                               (float*)d_out, N);
}